// Round 3
// baseline (1209.656 us; speedup 1.0000x reference)
//
#include <hip/hip_runtime.h>
#include <hip/hip_bf16.h>

// Hypergraph conv:  Xp = X@W;  Xe = mean_{v in e} Xp[v];
// Xv[v] = (1/att_sum[v]) * sum_{e ∋ v} homo[e]*Xe[e];  out = rowL2norm(Xp+Xv)
// Strategy: counting-sort both incidence views (edge-major and vertex-major CSR),
// then wave-per-segment reductions with lane = channel (64 ch == 64 lanes).
// Input float dtype (bf16 vs f32) and index width (i32 vs i64) are sniffed at
// runtime. OUTPUT is float32: the harness recomputes the reference in f32 from
// the (bf16-converted) inputs, so d_out carries the reference's f32 dtype.

__device__ __forceinline__ float bf2f(unsigned short u) {
    union { unsigned int i; float f; } x;
    x.i = ((unsigned int)u) << 16;
    return x.f;
}

__device__ __forceinline__ float loadF(const void* p, size_t i, int bf16mode) {
    return bf16mode ? bf2f(((const unsigned short*)p)[i]) : ((const float*)p)[i];
}

__device__ __forceinline__ int loadI(const void* p, size_t i, int i64mode) {
    // little-endian: low 32-bit word of an int64 holds the value (indices < 2^31)
    return i64mode ? ((const int*)p)[2 * i] : ((const int*)p)[i];
}

// ---------------- dtype sniff: flags[0]=floats-are-bf16, flags[1]=indices-are-i64
__global__ void sniff_kernel(const void* X, const void* vtx, int* flags) {
    if (threadIdx.x != 0 || blockIdx.x != 0) return;
    const unsigned short* u = (const unsigned short*)X;
    int sane = 0;
    for (int i = 0; i < 64; ++i) {
        unsigned short lo = u[2 * i];       // low half of 32-bit word i
        int e = (lo >> 7) & 0xFF;           // bf16 exponent field if data is bf16
        if (e >= 110 && e <= 137) ++sane;   // |x| in ~[2^-17, 2^10]
    }
    flags[0] = (sane >= 32) ? 1 : 0;
    const int* w = (const int*)vtx;
    int zeros = 0;
    for (int i = 0; i < 64; ++i)
        if (w[2 * i + 1] == 0) ++zeros;     // high halves of int64 are all zero
    flags[1] = (zeros >= 32) ? 1 : 0;
}

// ---------------- GEMM: Xp[N,64] = X[N,64] @ W[64,64], f32 out ----------------
__global__ void gemm_xp_kernel(const void* __restrict__ X,
                               const void* __restrict__ W,
                               const int* __restrict__ flags,
                               float* __restrict__ Xp, int N) {
    const int bmode = flags[0];
    int lane = threadIdx.x & 63;
    int wid  = (blockIdx.x * blockDim.x + threadIdx.x) >> 6;
    int nw   = (gridDim.x * blockDim.x) >> 6;
    float wcol[64];  // lane = output column; W column in registers
#pragma unroll
    for (int k = 0; k < 64; ++k) wcol[k] = loadF(W, (size_t)k * 64 + lane, bmode);
    if (bmode) {
        for (int r = wid; r < N; r += nw) {
            const ushort4* xr = (const ushort4*)((const unsigned short*)X + (size_t)r * 64);
            float acc = 0.f;
#pragma unroll
            for (int k4 = 0; k4 < 16; ++k4) {
                ushort4 u = xr[k4];  // wave-uniform broadcast load
                acc = fmaf(bf2f(u.x), wcol[4 * k4 + 0], acc);
                acc = fmaf(bf2f(u.y), wcol[4 * k4 + 1], acc);
                acc = fmaf(bf2f(u.z), wcol[4 * k4 + 2], acc);
                acc = fmaf(bf2f(u.w), wcol[4 * k4 + 3], acc);
            }
            Xp[(size_t)r * 64 + lane] = acc;
        }
    } else {
        for (int r = wid; r < N; r += nw) {
            const float4* xr = (const float4*)((const float*)X + (size_t)r * 64);
            float acc = 0.f;
#pragma unroll
            for (int k4 = 0; k4 < 16; ++k4) {
                float4 u = xr[k4];
                acc = fmaf(u.x, wcol[4 * k4 + 0], acc);
                acc = fmaf(u.y, wcol[4 * k4 + 1], acc);
                acc = fmaf(u.z, wcol[4 * k4 + 2], acc);
                acc = fmaf(u.w, wcol[4 * k4 + 3], acc);
            }
            Xp[(size_t)r * 64 + lane] = acc;
        }
    }
}

// ---------------- degree histograms + att_sum[v] = sum over incidences of homo[e]
__global__ void hist_kernel(const void* __restrict__ edges,
                            const void* __restrict__ vertex,
                            const void* __restrict__ homo,
                            const int* __restrict__ flags,
                            int* __restrict__ hist_e, int* __restrict__ hist_v,
                            float* __restrict__ att_sum, int nnz) {
    int i = blockIdx.x * blockDim.x + threadIdx.x;
    if (i >= nnz) return;
    int bmode = flags[0], imode = flags[1];
    int e = loadI(edges, i, imode);
    int v = loadI(vertex, i, imode);
    atomicAdd(&hist_e[e], 1);
    atomicAdd(&hist_v[v], 1);
    atomicAdd(&att_sum[v], loadF(homo, e, bmode));
}

// ---------------- exclusive scan (block0=edges, block1=verts), cursor copy, out[n]=total
__global__ void scan2_kernel(const int* __restrict__ hist_e, int* __restrict__ off_e,
                             int* __restrict__ cur_e, int nE,
                             const int* __restrict__ hist_v, int* __restrict__ off_v,
                             int* __restrict__ cur_v, int nV) {
    const int* in; int* out; int* cur; int n;
    if (blockIdx.x == 0) { in = hist_e; out = off_e; cur = cur_e; n = nE; }
    else                 { in = hist_v; out = off_v; cur = cur_v; n = nV; }

    __shared__ int wsum[16];
    __shared__ int carry_s;
    int tid = threadIdx.x, lane = tid & 63, w = tid >> 6;
    if (tid == 0) carry_s = 0;
    __syncthreads();

    for (int base = 0; base < n; base += 1024) {
        int i = base + tid;
        int x = (i < n) ? in[i] : 0;
        int s = x;  // wave inclusive scan
#pragma unroll
        for (int d = 1; d < 64; d <<= 1) {
            int t = __shfl_up(s, d, 64);
            if (lane >= d) s += t;
        }
        if (lane == 63) wsum[w] = s;
        __syncthreads();
        if (w == 0 && lane < 16) {  // scan the 16 wave sums
            int ws = wsum[lane];
#pragma unroll
            for (int d = 1; d < 16; d <<= 1) {
                int t = __shfl_up(ws, d, 64);
                if (lane >= d) ws += t;
            }
            wsum[lane] = ws;  // inclusive
        }
        __syncthreads();
        int carry = carry_s;
        int wpre  = (w > 0) ? wsum[w - 1] : 0;
        int excl  = carry + wpre + s - x;
        if (i < n) { out[i] = excl; cur[i] = excl; }
        __syncthreads();  // everyone read carry_s / wsum before update
        if (tid == 1023) carry_s = carry + wsum[15];
        __syncthreads();
    }
    if (tid == 0) out[n] = carry_s;
}

// ---------------- scatter incidences into both CSR orders -------------------
__global__ void scatter_kernel(const void* __restrict__ edges,
                               const void* __restrict__ vertex,
                               const int* __restrict__ flags,
                               int* __restrict__ cur_e, int* __restrict__ cur_v,
                               int* __restrict__ sorted_v_by_e,
                               int* __restrict__ sorted_e_by_v, int nnz) {
    int i = blockIdx.x * blockDim.x + threadIdx.x;
    if (i >= nnz) return;
    int imode = flags[1];
    int e = loadI(edges, i, imode);
    int v = loadI(vertex, i, imode);
    int p = atomicAdd(&cur_e[e], 1);
    sorted_v_by_e[p] = v;
    int q = atomicAdd(&cur_v[v], 1);
    sorted_e_by_v[q] = e;
}

// ---------------- Xe[e,:] = mean over incident vertices of Xp[v,:] ----------
__global__ void edge_mean_kernel(const float* __restrict__ Xp,
                                 const int* __restrict__ off_e,
                                 const int* __restrict__ sorted_v,
                                 float* __restrict__ Xe, int E) {
    int wid  = (blockIdx.x * blockDim.x + threadIdx.x) >> 6;
    int lane = threadIdx.x & 63;
    if (wid >= E) return;
    int start = off_e[wid], end = off_e[wid + 1];
    float acc = 0.f;
    int j = start;
    for (; j + 3 < end; j += 4) {  // 4-deep MLP
        int v0 = sorted_v[j], v1 = sorted_v[j + 1], v2 = sorted_v[j + 2], v3 = sorted_v[j + 3];
        float a0 = Xp[(size_t)v0 * 64 + lane];
        float a1 = Xp[(size_t)v1 * 64 + lane];
        float a2 = Xp[(size_t)v2 * 64 + lane];
        float a3 = Xp[(size_t)v3 * 64 + lane];
        acc += (a0 + a1) + (a2 + a3);
    }
    for (; j < end; ++j) acc += Xp[(size_t)sorted_v[j] * 64 + lane];
    float cnt = (float)(end - start);
    Xe[(size_t)wid * 64 + lane] = acc / fmaxf(cnt, 1.f);
}

// ---------------- out[v,:] = rowL2norm( Xp[v,:] + (1/att_sum)*sum homo[e]*Xe[e,:] )
__global__ void vertex_out_kernel(const float* __restrict__ Xp,
                                  const float* __restrict__ Xe,
                                  const int* __restrict__ off_v,
                                  const int* __restrict__ sorted_e,
                                  const void* __restrict__ homo,
                                  const int* __restrict__ flags,
                                  const float* __restrict__ att_sum,
                                  float* __restrict__ out, int N) {
    int wid  = (blockIdx.x * blockDim.x + threadIdx.x) >> 6;
    int lane = threadIdx.x & 63;
    if (wid >= N) return;
    int bmode = flags[0];
    int start = off_v[wid], end = off_v[wid + 1];
    float acc = 0.f;
    int j = start;
    for (; j + 3 < end; j += 4) {
        int e0 = sorted_e[j], e1 = sorted_e[j + 1], e2 = sorted_e[j + 2], e3 = sorted_e[j + 3];
        float h0 = loadF(homo, e0, bmode), h1 = loadF(homo, e1, bmode);
        float h2 = loadF(homo, e2, bmode), h3 = loadF(homo, e3, bmode);
        float a0 = Xe[(size_t)e0 * 64 + lane];
        float a1 = Xe[(size_t)e1 * 64 + lane];
        float a2 = Xe[(size_t)e2 * 64 + lane];
        float a3 = Xe[(size_t)e3 * 64 + lane];
        acc += h0 * a0 + h1 * a1 + h2 * a2 + h3 * a3;
    }
    for (; j < end; ++j) {
        int e = sorted_e[j];
        acc += loadF(homo, e, bmode) * Xe[(size_t)e * 64 + lane];
    }
    float asum = att_sum[wid];
    float xv   = (end > start && asum > 0.f) ? acc / asum : 0.f;
    float res  = Xp[(size_t)wid * 64 + lane] + xv;

    // row L2 norm across the 64 lanes
    float ss = res * res;
#pragma unroll
    for (int d = 32; d >= 1; d >>= 1) ss += __shfl_xor(ss, d, 64);
    float rn    = sqrtf(ss);
    float scale = (rn > 0.f) ? 1.f / fmaxf(rn, 1e-30f) : 0.f;
    out[(size_t)wid * 64 + lane] = res * scale;
}

extern "C" void kernel_launch(void* const* d_in, const int* in_sizes, int n_in,
                              void* d_out, int out_size, void* d_ws, size_t ws_size,
                              hipStream_t stream) {
    const void* X      = d_in[0];  // [N,64]  f32 or bf16 (sniffed)
    const void* W      = d_in[1];  // [64,64] f32 or bf16
    const void* homo   = d_in[2];  // [E]     f32 or bf16
    const void* vertex = d_in[3];  // [NNZ]   i32 or i64 (sniffed)
    const void* edges  = d_in[4];  // [NNZ]
    float* out = (float*)d_out;    // reference output dtype = float32

    const int N   = in_sizes[0] / 64;
    const int E   = in_sizes[2];
    const int NNZ = in_sizes[3];

    // ---- workspace carve-up (256B-aligned regions) ----
    char*  ws = (char*)d_ws;
    size_t o  = 0;
    auto alloc = [&](size_t bytes) -> void* {
        void* p = ws + o;
        o += (bytes + 255) & ~(size_t)255;
        return p;
    };
    int*   flags   = (int*)alloc(2 * 4);
    int*   off_e   = (int*)alloc((size_t)(E + 1) * 4);
    int*   off_v   = (int*)alloc((size_t)(N + 1) * 4);
    int*   hist_e  = (int*)alloc((size_t)E * 4);        // ---- zero region start
    int*   hist_v  = (int*)alloc((size_t)N * 4);
    float* att_sum = (float*)alloc((size_t)N * 4);      // ---- zero region end
    size_t zero_bytes = (size_t)((char*)att_sum - (char*)hist_e) + (size_t)N * 4;
    int*   cur_e   = (int*)alloc((size_t)E * 4);
    int*   cur_v   = (int*)alloc((size_t)N * 4);
    int*   sve     = (int*)alloc((size_t)NNZ * 4);      // vertices sorted by edge
    int*   sev     = (int*)alloc((size_t)NNZ * 4);      // edges sorted by vertex
    float* Xp      = (float*)alloc((size_t)N * 64 * 4);
    float* Xe      = (float*)alloc((size_t)E * 64 * 4);
    (void)ws_size; (void)n_in; (void)out_size;

    hipMemsetAsync(hist_e, 0, zero_bytes, stream);

    sniff_kernel<<<1, 64, 0, stream>>>(X, vertex, flags);

    gemm_xp_kernel<<<1024, 256, 0, stream>>>(X, W, flags, Xp, N);

    int nb = (NNZ + 255) / 256;
    hist_kernel<<<nb, 256, 0, stream>>>(edges, vertex, homo, flags, hist_e, hist_v, att_sum, NNZ);

    scan2_kernel<<<2, 1024, 0, stream>>>(hist_e, off_e, cur_e, E, hist_v, off_v, cur_v, N);

    scatter_kernel<<<nb, 256, 0, stream>>>(edges, vertex, flags, cur_e, cur_v, sve, sev, NNZ);

    edge_mean_kernel<<<(E + 3) / 4, 256, 0, stream>>>(Xp, off_e, sve, Xe, E);

    vertex_out_kernel<<<(N + 3) / 4, 256, 0, stream>>>(Xp, Xe, off_v, sev, homo, flags, att_sum, out, N);
}

// Round 4
// 790.220 us; speedup vs baseline: 1.5308x; 1.5308x over previous
//
#include <hip/hip_runtime.h>
#include <hip/hip_bf16.h>

// Hypergraph conv:  Xp = X@W;  Xe = mean_{v in e} Xp[v];
// Xv[v] = (sum_{e ∋ v} homo[e]*Xe[e]) / (sum_{e ∋ v} homo[e]);  out = rowL2norm(Xp+Xv)
// CSR build via slab counting-sort: per-chunk LDS histograms -> per-bin
// chunk-prefix -> LDS-rank scatter. NO global atomics in the fast path
// (round-3 counters showed the atomic pipeline was latency-bound:
// scatter 364us @ VALUBusy 0.33%, HBM 9%).

#define RB 16384  // bins per range: 64 KB LDS histogram (2 blocks/CU)

__device__ __forceinline__ float bf2f(unsigned short u) {
    union { unsigned int i; float f; } x;
    x.i = ((unsigned int)u) << 16;
    return x.f;
}

__device__ __forceinline__ float loadF(const void* p, size_t i, int bf16mode) {
    return bf16mode ? bf2f(((const unsigned short*)p)[i]) : ((const float*)p)[i];
}

__device__ __forceinline__ int loadI(const void* p, size_t i, int i64mode) {
    return i64mode ? ((const int*)p)[2 * i] : ((const int*)p)[i];
}

// ---------------- dtype sniff: flags[0]=floats-are-bf16, flags[1]=indices-are-i64
__global__ void sniff_kernel(const void* X, const void* vtx, int* flags) {
    if (threadIdx.x != 0 || blockIdx.x != 0) return;
    const unsigned short* u = (const unsigned short*)X;
    int sane = 0;
    for (int i = 0; i < 64; ++i) {
        unsigned short lo = u[2 * i];
        int e = (lo >> 7) & 0xFF;
        if (e >= 110 && e <= 137) ++sane;
    }
    flags[0] = (sane >= 32) ? 1 : 0;
    const int* w = (const int*)vtx;
    int zeros = 0;
    for (int i = 0; i < 64; ++i)
        if (w[2 * i + 1] == 0) ++zeros;
    flags[1] = (zeros >= 32) ? 1 : 0;
}

// ---------------- GEMM: Xp[N,64] = X[N,64] @ W[64,64], f32 out ----------------
__global__ void gemm_xp_kernel(const void* __restrict__ X,
                               const void* __restrict__ W,
                               const int* __restrict__ flags,
                               float* __restrict__ Xp, int N) {
    const int bmode = flags[0];
    int lane = threadIdx.x & 63;
    int wid  = (blockIdx.x * blockDim.x + threadIdx.x) >> 6;
    int nw   = (gridDim.x * blockDim.x) >> 6;
    float wcol[64];
#pragma unroll
    for (int k = 0; k < 64; ++k) wcol[k] = loadF(W, (size_t)k * 64 + lane, bmode);
    if (bmode) {
        for (int r = wid; r < N; r += nw) {
            const ushort4* xr = (const ushort4*)((const unsigned short*)X + (size_t)r * 64);
            float acc = 0.f;
#pragma unroll
            for (int k4 = 0; k4 < 16; ++k4) {
                ushort4 u = xr[k4];
                acc = fmaf(bf2f(u.x), wcol[4 * k4 + 0], acc);
                acc = fmaf(bf2f(u.y), wcol[4 * k4 + 1], acc);
                acc = fmaf(bf2f(u.z), wcol[4 * k4 + 2], acc);
                acc = fmaf(bf2f(u.w), wcol[4 * k4 + 3], acc);
            }
            Xp[(size_t)r * 64 + lane] = acc;
        }
    } else {
        for (int r = wid; r < N; r += nw) {
            const float4* xr = (const float4*)((const float*)X + (size_t)r * 64);
            float acc = 0.f;
#pragma unroll
            for (int k4 = 0; k4 < 16; ++k4) {
                float4 u = xr[k4];
                acc = fmaf(u.x, wcol[4 * k4 + 0], acc);
                acc = fmaf(u.y, wcol[4 * k4 + 1], acc);
                acc = fmaf(u.z, wcol[4 * k4 + 2], acc);
                acc = fmaf(u.w, wcol[4 * k4 + 3], acc);
            }
            Xp[(size_t)r * 64 + lane] = acc;
        }
    }
}

// ---------------- slab histogram: per-(chunk,range) LDS histogram ------------
// grid.x = B * (NRE + NRV); block b=id%B handles chunk [b*ce, min(nnz,(b+1)*ce))
__global__ __launch_bounds__(1024, 2)
void hist_slab_kernel(const void* __restrict__ edges,
                      const void* __restrict__ vertex,
                      const int* __restrict__ flags,
                      int* __restrict__ slab_e, int* __restrict__ slab_v,
                      int nnz, int E, int N, int B, int ce, int NRE) {
    __shared__ int cnt[RB];
    int b = blockIdx.x % B;
    int s = blockIdx.x / B;
    const void* keys; int* slab; int NB, r0;
    if (s < NRE) { keys = edges;  slab = slab_e; NB = E; r0 = s * RB; }
    else         { keys = vertex; slab = slab_v; NB = N; r0 = (s - NRE) * RB; }
    int rb = min(RB, NB - r0);
    int tid = threadIdx.x;
    for (int j = tid; j < rb; j += 1024) cnt[j] = 0;
    __syncthreads();
    int imode = flags[1];
    int c0 = b * ce, c1 = min(nnz, c0 + ce);
    for (int i = c0 + tid; i < c1; i += 1024) {
        int k = loadI(keys, i, imode) - r0;
        if ((unsigned)k < (unsigned)rb) atomicAdd(&cnt[k], 1);
    }
    __syncthreads();
    for (int j = tid; j < rb; j += 1024) slab[(size_t)b * NB + r0 + j] = cnt[j];
}

// ---------------- per-bin exclusive prefix over chunks (in place) + totals ----
__global__ void colscan_kernel(int* __restrict__ slab, int* __restrict__ totals,
                               int NB, int B) {
    int bin = blockIdx.x * blockDim.x + threadIdx.x;
    if (bin >= NB) return;
    int run = 0;
    for (int b = 0; b < B; ++b) {
        size_t idx = (size_t)b * NB + bin;
        int c = slab[idx];
        slab[idx] = run;
        run += c;
    }
    totals[bin] = run;
}

// ---------------- exclusive scan (block0=edges, block1=verts), out[n]=total ---
__global__ void scan2_kernel(const int* __restrict__ hist_e, int* __restrict__ off_e,
                             int* __restrict__ cur_e, int nE,
                             const int* __restrict__ hist_v, int* __restrict__ off_v,
                             int* __restrict__ cur_v, int nV) {
    const int* in; int* out; int* cur; int n;
    if (blockIdx.x == 0) { in = hist_e; out = off_e; cur = cur_e; n = nE; }
    else                 { in = hist_v; out = off_v; cur = cur_v; n = nV; }

    __shared__ int wsum[16];
    __shared__ int carry_s;
    int tid = threadIdx.x, lane = tid & 63, w = tid >> 6;
    if (tid == 0) carry_s = 0;
    __syncthreads();

    for (int base = 0; base < n; base += 1024) {
        int i = base + tid;
        int x = (i < n) ? in[i] : 0;
        int s = x;
#pragma unroll
        for (int d = 1; d < 64; d <<= 1) {
            int t = __shfl_up(s, d, 64);
            if (lane >= d) s += t;
        }
        if (lane == 63) wsum[w] = s;
        __syncthreads();
        if (w == 0 && lane < 16) {
            int ws = wsum[lane];
#pragma unroll
            for (int d = 1; d < 16; d <<= 1) {
                int t = __shfl_up(ws, d, 64);
                if (lane >= d) ws += t;
            }
            wsum[lane] = ws;
        }
        __syncthreads();
        int carry = carry_s;
        int wpre  = (w > 0) ? wsum[w - 1] : 0;
        int excl  = carry + wpre + s - x;
        if (i < n) { out[i] = excl; if (cur) cur[i] = excl; }
        __syncthreads();
        if (tid == 1023) carry_s = carry + wsum[15];
        __syncthreads();
    }
    if (tid == 0) out[n] = carry_s;
}

// ---------------- slab scatter: slot = off[k] + slabpref[b][k] + LDS rank -----
__global__ __launch_bounds__(1024, 2)
void scatter_slab_kernel(const void* __restrict__ edges,
                         const void* __restrict__ vertex,
                         const int* __restrict__ flags,
                         const int* __restrict__ slab_e, const int* __restrict__ slab_v,
                         const int* __restrict__ off_e, const int* __restrict__ off_v,
                         int* __restrict__ sve, int* __restrict__ sev,
                         int nnz, int E, int N, int B, int ce, int NRE) {
    __shared__ int cnt[RB];
    int b = blockIdx.x % B;
    int s = blockIdx.x / B;
    const void* keys; const void* payload; const int* slab; const int* off;
    int* dest; int NB, r0;
    if (s < NRE) { keys = edges;  payload = vertex; slab = slab_e; off = off_e;
                   dest = sve; NB = E; r0 = s * RB; }
    else         { keys = vertex; payload = edges;  slab = slab_v; off = off_v;
                   dest = sev; NB = N; r0 = (s - NRE) * RB; }
    int rb = min(RB, NB - r0);
    int tid = threadIdx.x;
    for (int j = tid; j < rb; j += 1024) cnt[j] = 0;
    __syncthreads();
    int imode = flags[1];
    int c0 = b * ce, c1 = min(nnz, c0 + ce);
    for (int i = c0 + tid; i < c1; i += 1024) {
        int k = loadI(keys, i, imode);
        int local = k - r0;
        if ((unsigned)local < (unsigned)rb) {
            int rank = atomicAdd(&cnt[local], 1);           // LDS atomic (cheap)
            int pos  = off[k] + slab[(size_t)b * NB + k] + rank;
            dest[pos] = loadI(payload, i, imode);
        }
    }
}

// ---------------- fallback (global-atomic) CSR build --------------------------
__global__ void hist2_kernel(const void* __restrict__ edges,
                             const void* __restrict__ vertex,
                             const int* __restrict__ flags,
                             int* __restrict__ hist_e, int* __restrict__ hist_v, int nnz) {
    int i = blockIdx.x * blockDim.x + threadIdx.x;
    if (i >= nnz) return;
    int imode = flags[1];
    atomicAdd(&hist_e[loadI(edges, i, imode)], 1);
    atomicAdd(&hist_v[loadI(vertex, i, imode)], 1);
}

__global__ void scatter_atomic_kernel(const void* __restrict__ edges,
                                      const void* __restrict__ vertex,
                                      const int* __restrict__ flags,
                                      int* __restrict__ cur_e, int* __restrict__ cur_v,
                                      int* __restrict__ sve, int* __restrict__ sev, int nnz) {
    int i = blockIdx.x * blockDim.x + threadIdx.x;
    if (i >= nnz) return;
    int imode = flags[1];
    int e = loadI(edges, i, imode);
    int v = loadI(vertex, i, imode);
    sve[atomicAdd(&cur_e[e], 1)] = v;
    sev[atomicAdd(&cur_v[v], 1)] = e;
}

// ---------------- Xe[e,:] = mean over incident vertices of Xp[v,:] ------------
__global__ void edge_mean_kernel(const float* __restrict__ Xp,
                                 const int* __restrict__ off_e,
                                 const int* __restrict__ sorted_v,
                                 float* __restrict__ Xe, int E) {
    int wid  = (blockIdx.x * blockDim.x + threadIdx.x) >> 6;
    int lane = threadIdx.x & 63;
    if (wid >= E) return;
    int start = off_e[wid], end = off_e[wid + 1];
    float acc = 0.f;
    int j = start;
    for (; j + 3 < end; j += 4) {
        int v0 = sorted_v[j], v1 = sorted_v[j + 1], v2 = sorted_v[j + 2], v3 = sorted_v[j + 3];
        float a0 = Xp[(size_t)v0 * 64 + lane];
        float a1 = Xp[(size_t)v1 * 64 + lane];
        float a2 = Xp[(size_t)v2 * 64 + lane];
        float a3 = Xp[(size_t)v3 * 64 + lane];
        acc += (a0 + a1) + (a2 + a3);
    }
    for (; j < end; ++j) acc += Xp[(size_t)sorted_v[j] * 64 + lane];
    float cnt = (float)(end - start);
    Xe[(size_t)wid * 64 + lane] = acc / fmaxf(cnt, 1.f);
}

// ---- out[v,:] = rowL2norm( Xp[v,:] + (sum homo[e]*Xe[e,:]) / (sum homo[e]) ) -
__global__ void vertex_out_kernel(const float* __restrict__ Xp,
                                  const float* __restrict__ Xe,
                                  const int* __restrict__ off_v,
                                  const int* __restrict__ sorted_e,
                                  const void* __restrict__ homo,
                                  const int* __restrict__ flags,
                                  float* __restrict__ out, int N) {
    int wid  = (blockIdx.x * blockDim.x + threadIdx.x) >> 6;
    int lane = threadIdx.x & 63;
    if (wid >= N) return;
    int bmode = flags[0];
    int start = off_v[wid], end = off_v[wid + 1];
    float acc = 0.f, hsum = 0.f;
    int j = start;
    for (; j + 3 < end; j += 4) {
        int e0 = sorted_e[j], e1 = sorted_e[j + 1], e2 = sorted_e[j + 2], e3 = sorted_e[j + 3];
        float h0 = loadF(homo, e0, bmode), h1 = loadF(homo, e1, bmode);
        float h2 = loadF(homo, e2, bmode), h3 = loadF(homo, e3, bmode);
        float a0 = Xe[(size_t)e0 * 64 + lane];
        float a1 = Xe[(size_t)e1 * 64 + lane];
        float a2 = Xe[(size_t)e2 * 64 + lane];
        float a3 = Xe[(size_t)e3 * 64 + lane];
        acc  += h0 * a0 + h1 * a1 + h2 * a2 + h3 * a3;
        hsum += (h0 + h1) + (h2 + h3);
    }
    for (; j < end; ++j) {
        int e = sorted_e[j];
        float h = loadF(homo, e, bmode);
        acc  += h * Xe[(size_t)e * 64 + lane];
        hsum += h;
    }
    float xv  = (end > start && hsum > 0.f) ? acc / hsum : 0.f;
    float res = Xp[(size_t)wid * 64 + lane] + xv;

    float ss = res * res;
#pragma unroll
    for (int d = 32; d >= 1; d >>= 1) ss += __shfl_xor(ss, d, 64);
    float rn    = sqrtf(ss);
    float scale = (rn > 0.f) ? 1.f / fmaxf(rn, 1e-30f) : 0.f;
    out[(size_t)wid * 64 + lane] = res * scale;
}

extern "C" void kernel_launch(void* const* d_in, const int* in_sizes, int n_in,
                              void* d_out, int out_size, void* d_ws, size_t ws_size,
                              hipStream_t stream) {
    const void* X      = d_in[0];
    const void* W      = d_in[1];
    const void* homo   = d_in[2];
    const void* vertex = d_in[3];
    const void* edges  = d_in[4];
    float* out = (float*)d_out;

    const int N   = in_sizes[0] / 64;
    const int E   = in_sizes[2];
    const int NNZ = in_sizes[3];

    const int B   = 128;
    const int ce  = (NNZ + B - 1) / B;
    const int NRE = (E + RB - 1) / RB;
    const int NRV = (N + RB - 1) / RB;

    char*  ws = (char*)d_ws;
    size_t o  = 0;
    auto alloc = [&](size_t bytes) -> void* {
        void* p = ws + o;
        o += (bytes + 255) & ~(size_t)255;
        return p;
    };
    int*   flags = (int*)alloc(2 * 4);
    int*   off_e = (int*)alloc((size_t)(E + 1) * 4);
    int*   off_v = (int*)alloc((size_t)(N + 1) * 4);
    int*   tot_e = (int*)alloc((size_t)E * 4);   // fast: totals; fallback: hist
    int*   tot_v = (int*)alloc((size_t)N * 4);
    int*   sve   = (int*)alloc((size_t)NNZ * 4);
    int*   sev   = (int*)alloc((size_t)NNZ * 4);
    float* Xp    = (float*)alloc((size_t)N * 64 * 4);
    float* Xe    = (float*)alloc((size_t)E * 64 * 4);
    size_t o_common = o;
    int* slab_e = (int*)alloc((size_t)B * E * 4);
    int* slab_v = (int*)alloc((size_t)B * N * 4);
    bool fast = (o <= ws_size);
    (void)n_in; (void)out_size;

    sniff_kernel<<<1, 64, 0, stream>>>(X, vertex, flags);
    gemm_xp_kernel<<<1024, 256, 0, stream>>>(X, W, flags, Xp, N);

    if (fast) {
        hist_slab_kernel<<<B * (NRE + NRV), 1024, 0, stream>>>(
            edges, vertex, flags, slab_e, slab_v, NNZ, E, N, B, ce, NRE);
        colscan_kernel<<<(E + 255) / 256, 256, 0, stream>>>(slab_e, tot_e, E, B);
        colscan_kernel<<<(N + 255) / 256, 256, 0, stream>>>(slab_v, tot_v, N, B);
        scan2_kernel<<<2, 1024, 0, stream>>>(tot_e, off_e, nullptr, E,
                                             tot_v, off_v, nullptr, N);
        scatter_slab_kernel<<<B * (NRE + NRV), 1024, 0, stream>>>(
            edges, vertex, flags, slab_e, slab_v, off_e, off_v,
            sve, sev, NNZ, E, N, B, ce, NRE);
    } else {
        // fallback: global-atomic CSR build in the slab region (smaller)
        o = o_common;
        int* cur_e = (int*)alloc((size_t)E * 4);
        int* cur_v = (int*)alloc((size_t)N * 4);
        hipMemsetAsync(tot_e, 0, (size_t)((char*)(tot_v + N) - (char*)tot_e), stream);
        int nb = (NNZ + 255) / 256;
        hist2_kernel<<<nb, 256, 0, stream>>>(edges, vertex, flags, tot_e, tot_v, NNZ);
        scan2_kernel<<<2, 1024, 0, stream>>>(tot_e, off_e, cur_e, E,
                                             tot_v, off_v, cur_v, N);
        scatter_atomic_kernel<<<nb, 256, 0, stream>>>(edges, vertex, flags,
                                                      cur_e, cur_v, sve, sev, NNZ);
    }

    edge_mean_kernel<<<(E + 3) / 4, 256, 0, stream>>>(Xp, off_e, sve, Xe, E);
    vertex_out_kernel<<<(N + 3) / 4, 256, 0, stream>>>(Xp, Xe, off_v, sev,
                                                       homo, flags, out, N);
}

// Round 5
// 466.612 us; speedup vs baseline: 2.5924x; 1.6935x over previous
//
#include <hip/hip_runtime.h>
#include <hip/hip_bf16.h>

// Hypergraph conv:  Xp = X@W;  Xe = mean_{v in e} Xp[v];
// Xv[v] = (sum_{e ∋ v} homo[e]*Xe[e]) / (sum_{e ∋ v} homo[e]);  out = rowL2norm(Xp+Xv)
//
// R4 counters: gemm was scratch-spill bound (wcol[64]/thread -> 442 MB FETCH).
// v2: W in LDS, 4-row unroll. CSR build: u16-packed LDS histograms over a
// concatenated (E+N) bin space, parallel 3-phase scan, slab scatter with LDS
// ranks. Gathered payloads (Xp for edge_mean, Xe for vertex_out) in bf16.

#define RBINS 32768  // bins per LDS pass, u16-packed -> 64 KB LDS

__device__ __forceinline__ float bf2f(unsigned short u) {
    union { unsigned int i; float f; } x;
    x.i = ((unsigned int)u) << 16;
    return x.f;
}

__device__ __forceinline__ unsigned short f2bf(float f) {
    union { unsigned int i; float ff; } x;
    x.ff = f;
    unsigned int r = x.i + 0x7fff + ((x.i >> 16) & 1);  // round-to-nearest-even
    return (unsigned short)(r >> 16);
}

__device__ __forceinline__ float loadF(const void* p, size_t i, int bf16mode) {
    return bf16mode ? bf2f(((const unsigned short*)p)[i]) : ((const float*)p)[i];
}

__device__ __forceinline__ int loadI(const void* p, size_t i, int i64mode) {
    return i64mode ? ((const int*)p)[2 * i] : ((const int*)p)[i];
}

// ---------------- dtype sniff: flags[0]=floats-are-bf16, flags[1]=indices-are-i64
__global__ void sniff_kernel(const void* X, const void* vtx, int* flags) {
    if (threadIdx.x != 0 || blockIdx.x != 0) return;
    const unsigned short* u = (const unsigned short*)X;
    int sane = 0;
    for (int i = 0; i < 64; ++i) {
        unsigned short lo = u[2 * i];
        int e = (lo >> 7) & 0xFF;
        if (e >= 110 && e <= 137) ++sane;
    }
    flags[0] = (sane >= 32) ? 1 : 0;
    const int* w = (const int*)vtx;
    int zeros = 0;
    for (int i = 0; i < 64; ++i)
        if (w[2 * i + 1] == 0) ++zeros;
    flags[1] = (zeros >= 32) ? 1 : 0;
}

// ---------------- GEMM v2: W in LDS, 4-row unroll; writes Xp f32 + Xpb bf16 ---
__global__ __launch_bounds__(256)
void gemm_kernel(const void* __restrict__ X, const void* __restrict__ W,
                 const int* __restrict__ flags,
                 float* __restrict__ Xp, unsigned short* __restrict__ Xpb, int N) {
    __shared__ float Ws[64 * 64];   // Ws[k*64+c]: lanes hit bank c%32 (2-way, free)
    __shared__ float Xs[16][64];    // 4 waves x 4 rows
    const int bmode = flags[0];
    int tid = threadIdx.x;
    for (int j = tid; j < 4096; j += 256) Ws[j] = loadF(W, j, bmode);
    __syncthreads();
    int lane = tid & 63, w = tid >> 6;
    int wid = (blockIdx.x * 256 + tid) >> 6;
    int nw  = (gridDim.x * 256) >> 6;
    for (int r0 = wid * 4; r0 < N; r0 += nw * 4) {
        if (r0 + 4 <= N) {
            float acc0 = 0.f, acc1 = 0.f, acc2 = 0.f, acc3 = 0.f;
#pragma unroll
            for (int j = 0; j < 4; ++j)
                Xs[w * 4 + j][lane] = loadF(X, (size_t)(r0 + j) * 64 + lane, bmode);
            // same wave writes & reads its own Xs rows: no barrier needed
#pragma unroll
            for (int k4 = 0; k4 < 16; ++k4) {
                float4 x0 = *(const float4*)&Xs[w * 4 + 0][k4 * 4];
                float4 x1 = *(const float4*)&Xs[w * 4 + 1][k4 * 4];
                float4 x2 = *(const float4*)&Xs[w * 4 + 2][k4 * 4];
                float4 x3 = *(const float4*)&Xs[w * 4 + 3][k4 * 4];
#pragma unroll
                for (int kk = 0; kk < 4; ++kk) {
                    float wv = Ws[(k4 * 4 + kk) * 64 + lane];
                    float e0 = (&x0.x)[kk], e1 = (&x1.x)[kk];
                    float e2 = (&x2.x)[kk], e3 = (&x3.x)[kk];
                    acc0 = fmaf(e0, wv, acc0);
                    acc1 = fmaf(e1, wv, acc1);
                    acc2 = fmaf(e2, wv, acc2);
                    acc3 = fmaf(e3, wv, acc3);
                }
            }
            float a[4] = {acc0, acc1, acc2, acc3};
#pragma unroll
            for (int j = 0; j < 4; ++j) {
                Xp[(size_t)(r0 + j) * 64 + lane]  = a[j];
                Xpb[(size_t)(r0 + j) * 64 + lane] = f2bf(a[j]);
            }
        } else {
            for (int r = r0; r < N; ++r) {
                Xs[w * 4][lane] = loadF(X, (size_t)r * 64 + lane, bmode);
                float acc = 0.f;
                for (int k = 0; k < 64; ++k)
                    acc = fmaf(Xs[w * 4][k], Ws[k * 64 + lane], acc);
                Xp[(size_t)r * 64 + lane]  = acc;
                Xpb[(size_t)r * 64 + lane] = f2bf(acc);
            }
        }
    }
}

// ---------------- slab histogram: u16-packed LDS counts, conc bin space ------
__global__ __launch_bounds__(1024, 2)
void hist_slab_kernel(const void* __restrict__ edges,
                      const void* __restrict__ vertex,
                      const int* __restrict__ flags,
                      int* __restrict__ slab,
                      int nnz, int E, int N, int B, int ce, int NRE) {
    __shared__ unsigned int cnt[RBINS / 2];  // 64 KB
    int b = blockIdx.x % B;
    int s = blockIdx.x / B;
    const void* keys; int r0, nb_, base;
    const int M = E + N;
    if (s < NRE) { keys = edges;  r0 = s * RBINS;         nb_ = min(RBINS, E - r0); base = r0; }
    else         { keys = vertex; r0 = (s - NRE) * RBINS; nb_ = min(RBINS, N - r0); base = E + r0; }
    int tid = threadIdx.x;
    for (int j = tid; j < RBINS / 2; j += 1024) cnt[j] = 0;
    __syncthreads();
    int imode = flags[1];
    int c0 = b * ce, c1 = min(nnz, c0 + ce);
    for (int i = c0 + tid; i < c1; i += 1024) {
        int k = loadI(keys, i, imode) - r0;
        if ((unsigned)k < (unsigned)nb_)
            atomicAdd(&cnt[k >> 1], (k & 1) ? 0x10000u : 1u);
    }
    __syncthreads();
    for (int j = tid; j < nb_; j += 1024) {
        unsigned int c = cnt[j >> 1];
        slab[(size_t)b * M + base + j] = (j & 1) ? (int)(c >> 16) : (int)(c & 0xffffu);
    }
}

// ---------------- per-bin exclusive prefix over chunks (in place) + totals ---
__global__ void colscan_kernel(int* __restrict__ slab, int* __restrict__ tot,
                               int M, int B) {
    int bin = blockIdx.x * 256 + threadIdx.x;
    if (bin >= M) return;
    int run = 0;
    for (int b = 0; b < B; ++b) {
        size_t idx = (size_t)b * M + bin;
        int c = slab[idx];
        slab[idx] = run;
        run += c;
    }
    tot[bin] = run;
}

// ---------------- parallel exclusive scan, 3 phases (tile = 2048) ------------
__global__ void scan_part_kernel(const int* __restrict__ tot, int* __restrict__ part, int M) {
    int g = blockIdx.x, tid = threadIdx.x;
    int base = g * 2048;
    int sum = 0;
    for (int j = tid; j < 2048; j += 256) {
        int i = base + j;
        sum += (i < M) ? tot[i] : 0;
    }
#pragma unroll
    for (int d = 32; d >= 1; d >>= 1) sum += __shfl_xor(sum, d, 64);
    __shared__ int wsums[4];
    int lane = tid & 63, w = tid >> 6;
    if (lane == 0) wsums[w] = sum;
    __syncthreads();
    if (tid == 0) part[g] = wsums[0] + wsums[1] + wsums[2] + wsums[3];
}

__global__ void scan_root_kernel(int* __restrict__ part, int G,
                                 int* __restrict__ off, int M) {
    // single block of 1024; G <= 1024
    int tid = threadIdx.x, lane = tid & 63, w = tid >> 6;
    int x = (tid < G) ? part[tid] : 0;
    int s = x;
#pragma unroll
    for (int d = 1; d < 64; d <<= 1) {
        int t = __shfl_up(s, d, 64);
        if (lane >= d) s += t;
    }
    __shared__ int ws[16];
    if (lane == 63) ws[w] = s;
    __syncthreads();
    if (w == 0 && lane < 16) {
        int v = ws[lane];
#pragma unroll
        for (int d = 1; d < 16; d <<= 1) {
            int t = __shfl_up(v, d, 64);
            if (lane >= d) v += t;
        }
        ws[lane] = v;
    }
    __syncthreads();
    int excl = s - x + (w > 0 ? ws[w - 1] : 0);
    if (tid < G) part[tid] = excl;
    if (tid == 1023) off[M] = ws[15];  // grand total = 2*NNZ
}

__global__ void scan_apply_kernel(const int* __restrict__ tot, const int* __restrict__ part,
                                  int* __restrict__ off, int M) {
    int g = blockIdx.x, tid = threadIdx.x, lane = tid & 63, w = tid >> 6;
    int base = g * 2048 + tid * 8;
    int e[8]; int s = 0;
#pragma unroll
    for (int j = 0; j < 8; ++j) {
        int i = base + j;
        e[j] = (i < M) ? tot[i] : 0;
        s += e[j];
    }
    int si = s;
#pragma unroll
    for (int d = 1; d < 64; d <<= 1) {
        int t = __shfl_up(si, d, 64);
        if (lane >= d) si += t;
    }
    __shared__ int wsum[4];
    if (lane == 63) wsum[w] = si;
    __syncthreads();
    int wbase = 0;
    for (int ww = 0; ww < w; ++ww) wbase += wsum[ww];
    int run = part[g] + wbase + si - s;
#pragma unroll
    for (int j = 0; j < 8; ++j) {
        int i = base + j;
        if (i < M) off[i] = run;
        run += e[j];
    }
}

// ---------------- slab scatter: u16 LDS ranks, one dest array ----------------
__global__ __launch_bounds__(1024, 2)
void scatter_slab_kernel(const void* __restrict__ edges,
                         const void* __restrict__ vertex,
                         const int* __restrict__ flags,
                         const int* __restrict__ slab, const int* __restrict__ off,
                         int* __restrict__ dest,
                         int nnz, int E, int N, int B, int ce, int NRE) {
    __shared__ unsigned int cnt[RBINS / 2];
    int b = blockIdx.x % B;
    int s = blockIdx.x / B;
    const void* keys; const void* pay; int r0, nb_, base;
    const int M = E + N;
    if (s < NRE) { keys = edges;  pay = vertex; r0 = s * RBINS;         nb_ = min(RBINS, E - r0); base = r0; }
    else         { keys = vertex; pay = edges;  r0 = (s - NRE) * RBINS; nb_ = min(RBINS, N - r0); base = E + r0; }
    int tid = threadIdx.x;
    for (int j = tid; j < RBINS / 2; j += 1024) cnt[j] = 0;
    __syncthreads();
    int imode = flags[1];
    int c0 = b * ce, c1 = min(nnz, c0 + ce);
    for (int i = c0 + tid; i < c1; i += 1024) {
        int k = loadI(keys, i, imode) - r0;
        if ((unsigned)k < (unsigned)nb_) {
            unsigned int old = atomicAdd(&cnt[k >> 1], (k & 1) ? 0x10000u : 1u);
            int rank = (k & 1) ? (int)(old >> 16) : (int)(old & 0xffffu);
            int bin  = base + k;
            int pos  = off[bin] + slab[(size_t)b * M + bin] + rank;
            dest[pos] = loadI(pay, i, imode);
        }
    }
}

// ---------------- fallback (global-atomic) CSR build -------------------------
__global__ void hist_atomic_kernel(const void* __restrict__ edges,
                                   const void* __restrict__ vertex,
                                   const int* __restrict__ flags,
                                   int* __restrict__ tot, int E, int nnz) {
    int i = blockIdx.x * blockDim.x + threadIdx.x;
    if (i >= nnz) return;
    int imode = flags[1];
    atomicAdd(&tot[loadI(edges, i, imode)], 1);
    atomicAdd(&tot[E + loadI(vertex, i, imode)], 1);
}

__global__ void copy_kernel(const int* __restrict__ src, int* __restrict__ dst, int n) {
    int i = blockIdx.x * blockDim.x + threadIdx.x;
    if (i < n) dst[i] = src[i];
}

__global__ void scatter_atomic_kernel(const void* __restrict__ edges,
                                      const void* __restrict__ vertex,
                                      const int* __restrict__ flags,
                                      int* __restrict__ cur, int* __restrict__ dest,
                                      int E, int nnz) {
    int i = blockIdx.x * blockDim.x + threadIdx.x;
    if (i >= nnz) return;
    int imode = flags[1];
    int e = loadI(edges, i, imode);
    int v = loadI(vertex, i, imode);
    dest[atomicAdd(&cur[e], 1)]     = v;
    dest[atomicAdd(&cur[E + v], 1)] = e;
}

// ---------------- Xe[e,:] = mean over incident vertices of Xpb[v,:] ----------
__global__ void edge_mean_kernel(const unsigned short* __restrict__ Xpb,
                                 const int* __restrict__ off,
                                 const int* __restrict__ sorted,
                                 unsigned short* __restrict__ Xe, int E) {
    int wid  = (blockIdx.x * blockDim.x + threadIdx.x) >> 6;
    int lane = threadIdx.x & 63;
    if (wid >= E) return;
    int start = off[wid], end = off[wid + 1];
    float acc = 0.f;
    int j = start;
    for (; j + 3 < end; j += 4) {
        int v0 = sorted[j], v1 = sorted[j + 1], v2 = sorted[j + 2], v3 = sorted[j + 3];
        float a0 = bf2f(Xpb[(size_t)v0 * 64 + lane]);
        float a1 = bf2f(Xpb[(size_t)v1 * 64 + lane]);
        float a2 = bf2f(Xpb[(size_t)v2 * 64 + lane]);
        float a3 = bf2f(Xpb[(size_t)v3 * 64 + lane]);
        acc += (a0 + a1) + (a2 + a3);
    }
    for (; j < end; ++j) acc += bf2f(Xpb[(size_t)sorted[j] * 64 + lane]);
    float cnt = (float)(end - start);
    Xe[(size_t)wid * 64 + lane] = f2bf(acc / fmaxf(cnt, 1.f));
}

// ---- out[v,:] = rowL2norm( Xp[v,:] + (sum homo[e]*Xe[e,:]) / (sum homo[e]) )
__global__ void vertex_out_kernel(const float* __restrict__ Xp,
                                  const unsigned short* __restrict__ Xe,
                                  const int* __restrict__ off,
                                  const int* __restrict__ sorted,
                                  const void* __restrict__ homo,
                                  const int* __restrict__ flags,
                                  float* __restrict__ out, int E, int N) {
    int wid  = (blockIdx.x * blockDim.x + threadIdx.x) >> 6;
    int lane = threadIdx.x & 63;
    if (wid >= N) return;
    int bmode = flags[0];
    int start = off[E + wid], end = off[E + wid + 1];
    float acc = 0.f, hsum = 0.f;
    int j = start;
    for (; j + 3 < end; j += 4) {
        int e0 = sorted[j], e1 = sorted[j + 1], e2 = sorted[j + 2], e3 = sorted[j + 3];
        float h0 = loadF(homo, e0, bmode), h1 = loadF(homo, e1, bmode);
        float h2 = loadF(homo, e2, bmode), h3 = loadF(homo, e3, bmode);
        float a0 = bf2f(Xe[(size_t)e0 * 64 + lane]);
        float a1 = bf2f(Xe[(size_t)e1 * 64 + lane]);
        float a2 = bf2f(Xe[(size_t)e2 * 64 + lane]);
        float a3 = bf2f(Xe[(size_t)e3 * 64 + lane]);
        acc  += h0 * a0 + h1 * a1 + h2 * a2 + h3 * a3;
        hsum += (h0 + h1) + (h2 + h3);
    }
    for (; j < end; ++j) {
        int e = sorted[j];
        float h = loadF(homo, e, bmode);
        acc  += h * bf2f(Xe[(size_t)e * 64 + lane]);
        hsum += h;
    }
    float xv  = (end > start && hsum > 0.f) ? acc / hsum : 0.f;
    float res = Xp[(size_t)wid * 64 + lane] + xv;

    float ss = res * res;
#pragma unroll
    for (int d = 32; d >= 1; d >>= 1) ss += __shfl_xor(ss, d, 64);
    float rn    = sqrtf(ss);
    float scale = (rn > 0.f) ? 1.f / fmaxf(rn, 1e-30f) : 0.f;
    out[(size_t)wid * 64 + lane] = res * scale;
}

extern "C" void kernel_launch(void* const* d_in, const int* in_sizes, int n_in,
                              void* d_out, int out_size, void* d_ws, size_t ws_size,
                              hipStream_t stream) {
    const void* X      = d_in[0];
    const void* W      = d_in[1];
    const void* homo   = d_in[2];
    const void* vertex = d_in[3];
    const void* edges  = d_in[4];
    float* out = (float*)d_out;

    const int N   = in_sizes[0] / 64;
    const int E   = in_sizes[2];
    const int NNZ = in_sizes[3];
    const int M   = E + N;

    const int B   = 64;                       // chunks; ce < 65536 for u16 ranks
    const int ce  = (NNZ + B - 1) / B;
    const int NRE = (E + RBINS - 1) / RBINS;
    const int NRV = (N + RBINS - 1) / RBINS;
    const int G   = (M + 2047) / 2048;        // scan tiles (<= 1024)

    char*  ws = (char*)d_ws;
    size_t o  = 0;
    auto alloc = [&](size_t bytes) -> void* {
        void* p = ws + o;
        o += (bytes + 255) & ~(size_t)255;
        return p;
    };
    int*            flags = (int*)alloc(2 * 4);
    int*            off   = (int*)alloc((size_t)(M + 1) * 4);   // conc offsets
    int*            tot   = (int*)alloc((size_t)M * 4);
    int*            part  = (int*)alloc((size_t)(G + 1) * 4);
    int*            sorted= (int*)alloc((size_t)2 * NNZ * 4);   // [0,NNZ)=v-by-e, [NNZ,2NNZ)=e-by-v
    float*          Xp    = (float*)alloc((size_t)N * 64 * 4);
    unsigned short* Xpb   = (unsigned short*)alloc((size_t)N * 64 * 2);
    unsigned short* Xe    = (unsigned short*)alloc((size_t)E * 64 * 2);
    size_t o_common = o;
    int*            slab  = (int*)alloc((size_t)B * M * 4);
    bool fast = (o <= ws_size) && (ce < 65536) && (G <= 1024);
    (void)n_in; (void)out_size;

    sniff_kernel<<<1, 64, 0, stream>>>(X, vertex, flags);
    gemm_kernel<<<512, 256, 0, stream>>>(X, W, flags, Xp, Xpb, N);

    if (fast) {
        hist_slab_kernel<<<B * (NRE + NRV), 1024, 0, stream>>>(
            edges, vertex, flags, slab, NNZ, E, N, B, ce, NRE);
        colscan_kernel<<<(M + 255) / 256, 256, 0, stream>>>(slab, tot, M, B);
        scan_part_kernel<<<G, 256, 0, stream>>>(tot, part, M);
        scan_root_kernel<<<1, 1024, 0, stream>>>(part, G, off, M);
        scan_apply_kernel<<<G, 256, 0, stream>>>(tot, part, off, M);
        scatter_slab_kernel<<<B * (NRE + NRV), 1024, 0, stream>>>(
            edges, vertex, flags, slab, off, sorted, NNZ, E, N, B, ce, NRE);
    } else {
        o = o_common;
        int* cur = (int*)alloc((size_t)M * 4);
        hipMemsetAsync(tot, 0, (size_t)M * 4, stream);
        int nb = (NNZ + 255) / 256;
        hist_atomic_kernel<<<nb, 256, 0, stream>>>(edges, vertex, flags, tot, E, NNZ);
        scan_part_kernel<<<G, 256, 0, stream>>>(tot, part, M);
        scan_root_kernel<<<1, 1024, 0, stream>>>(part, G, off, M);
        scan_apply_kernel<<<G, 256, 0, stream>>>(tot, part, off, M);
        copy_kernel<<<(M + 255) / 256, 256, 0, stream>>>(off, cur, M);
        scatter_atomic_kernel<<<nb, 256, 0, stream>>>(edges, vertex, flags, cur, sorted, E, NNZ);
    }

    edge_mean_kernel<<<(E + 3) / 4, 256, 0, stream>>>(Xpb, off, sorted, Xe, E);
    vertex_out_kernel<<<(N + 3) / 4, 256, 0, stream>>>(Xp, Xe, off, sorted,
                                                       homo, flags, out, E, N);
}